// Round 13
// baseline (176.293 us; speedup 1.0000x reference)
//
#include <hip/hip_runtime.h>

#define DIN 128
#define DHID 128
#define DOUT 64
#define CAPB 6144    // bin capacity per 256-node range (mean ~4082, sigma ~64)
#define CHUNK 4096   // edges per binA block
#define EPT (CHUNK / 256)

typedef short bf16x8 __attribute__((ext_vector_type(8)));
typedef float f32x4 __attribute__((ext_vector_type(4)));

// ---- bf16 helpers ---------------------------------------------------------
static __device__ __forceinline__ unsigned short f2bf(float f) {
  union { float f; unsigned u; } v; v.f = f;
  unsigned r = v.u + 0x7fffu + ((v.u >> 16) & 1u);  // round-nearest-even
  return (unsigned short)(r >> 16);
}
static __device__ __forceinline__ float bf_lo(unsigned v) {
  union { unsigned u; float f; } t; t.u = v << 16; return t.f;
}
static __device__ __forceinline__ float bf_hi(unsigned v) {
  union { unsigned u; float f; } t; t.u = v & 0xffff0000u; return t.f;
}

// ---------------------------------------------------------------------------
// init: zero bincursor + frag-order bf16 conversion of W1/W2 (one launch).
// ---------------------------------------------------------------------------
static __device__ __forceinline__ void wcast_body(
    const float* __restrict__ W, unsigned short* __restrict__ Wf,
    int NOUT, int tid) {
  int f = tid >> 6;
  int lane = tid & 63;
  int t = f & 3;
  int nt = f >> 2;
  int kbase = t * 32 + (lane >> 4) * 8;
  int n = nt * 16 + (lane & 15);
#pragma unroll
  for (int j = 0; j < 8; ++j)
    Wf[(size_t)tid * 8 + j] = f2bf(W[(size_t)(kbase + j) * NOUT + n]);
}

__global__ __launch_bounds__(256) void init_kernel(
    const float* __restrict__ W1, const float* __restrict__ W2,
    unsigned short* __restrict__ Wf1, unsigned short* __restrict__ Wf2,
    int* __restrict__ bincursor) {
  const int b = blockIdx.x;
  const int t = threadIdx.x;
  if (b == 0) {
    bincursor[t] = 0;
  } else if (b <= 8) {
    wcast_body(W1, Wf1, DHID, (b - 1) * 256 + t);
  } else {
    wcast_body(W2, Wf2, DOUT, (b - 9) * 256 + t);
  }
}

// ---------------------------------------------------------------------------
// gemm1 tile: 64 rows of C[M,128](bf16) = A[M,128](fp32) * Wf1 (regs).
// ---------------------------------------------------------------------------
static __device__ void gemm1_tile(
    const float* __restrict__ A, const unsigned short* __restrict__ Wf,
    unsigned short* __restrict__ C, int M, int tile) {
  constexpr int NT = DHID / 16;  // 8
  const int lane = threadIdx.x & 63;
  const int wave = threadIdx.x >> 6;
  const int g = lane >> 4;
  const int m15 = lane & 15;

  bf16x8 bfrag[NT * 4];
#pragma unroll
  for (int f = 0; f < NT * 4; ++f)
    bfrag[f] = *(const bf16x8*)(Wf + ((size_t)(f * 64 + lane)) * 8);

  const int rowbase = tile * 64 + wave * 16;
  if (rowbase >= M) return;
  f32x4 acc[NT];
#pragma unroll
  for (int nt = 0; nt < NT; ++nt) acc[nt] = (f32x4){0.f, 0.f, 0.f, 0.f};
  const float* arow = A + (size_t)(rowbase + m15) * 128 + g * 8;
  bf16x8 af[4];
#pragma unroll
  for (int t = 0; t < 4; ++t) {
    float4 a0 = *(const float4*)(arow + t * 32);
    float4 a1 = *(const float4*)(arow + t * 32 + 4);
    bf16x8 f;
    f[0] = (short)f2bf(a0.x); f[1] = (short)f2bf(a0.y);
    f[2] = (short)f2bf(a0.z); f[3] = (short)f2bf(a0.w);
    f[4] = (short)f2bf(a1.x); f[5] = (short)f2bf(a1.y);
    f[6] = (short)f2bf(a1.z); f[7] = (short)f2bf(a1.w);
    af[t] = f;
  }
#pragma unroll
  for (int t = 0; t < 4; ++t)
#pragma unroll
    for (int nt = 0; nt < NT; ++nt)
      acc[nt] = __builtin_amdgcn_mfma_f32_16x16x32_bf16(
          af[t], bfrag[nt * 4 + t], acc[nt], 0, 0, 0);
#pragma unroll
  for (int nt = 0; nt < NT; ++nt)
#pragma unroll
    for (int r = 0; r < 4; ++r) {
      int row = rowbase + g * 4 + r;
      if (row < M)
        C[(size_t)row * DHID + nt * 16 + m15] = f2bf(acc[nt][r]);
    }
}

// ---------------------------------------------------------------------------
// phaseA: blocks [0,nbinA) bin edges by range (LDS, burst writes); blocks
// [nbinA, nbinA+ntiles) each run one gemm1 tile (independent -> overlap).
// ---------------------------------------------------------------------------
__global__ __launch_bounds__(256) void phaseA_kernel(
    const int* __restrict__ src, const int* __restrict__ dst,
    int* __restrict__ bincursor, unsigned* __restrict__ binbuf, int E,
    int nbinA, const float* __restrict__ x,
    const unsigned short* __restrict__ Wf1, unsigned short* __restrict__ h1,
    int M) {
  __shared__ int hist[256];
  __shared__ int cnt[256];
  __shared__ int offs[256];
  __shared__ int cur[256];
  __shared__ int gbase[256];
  __shared__ unsigned stage[CHUNK];

  if ((int)blockIdx.x >= nbinA) {
    gemm1_tile(x, Wf1, h1, M, (int)blockIdx.x - nbinA);
    return;
  }

  const int t = threadIdx.x;
  const int base = blockIdx.x * CHUNK;
  const int n = min(CHUNK, E - base);

  hist[t] = 0;
  __syncthreads();

  unsigned rec[EPT];
  int rng[EPT];
#pragma unroll
  for (int j = 0; j < EPT; ++j) {
    int e = base + j * 256 + t;
    rng[j] = -1;
    if (e < E) {
      int d = dst[e];
      int s = src[e];
      int r = d >> 8;
      rng[j] = r;
      rec[j] = (unsigned)s | ((unsigned)(d & 255) << 16) | ((unsigned)r << 24);
      atomicAdd(&hist[r], 1);
    }
  }
  __syncthreads();
  int myc = hist[t];
  cnt[t] = myc;
  __syncthreads();
#pragma unroll
  for (int o = 1; o < 256; o <<= 1) {
    int u = (t >= o) ? hist[t - o] : 0;
    __syncthreads();
    hist[t] += u;
    __syncthreads();
  }
  offs[t] = hist[t] - myc;
  cur[t] = hist[t] - myc;
  __syncthreads();
#pragma unroll
  for (int j = 0; j < EPT; ++j) {
    if (rng[j] >= 0) {
      int pos = atomicAdd(&cur[rng[j]], 1);
      stage[pos] = rec[j];
    }
  }
  __syncthreads();
  int c = cnt[t];
  gbase[t] = c ? atomicAdd(&bincursor[t], c) : 0;
  __syncthreads();
  for (int i = t; i < n; i += 256) {
    unsigned v = stage[i];
    int r = v >> 24;
    int local = i - offs[r];
    int gpos = gbase[r] + local;
    if (gpos < CAPB) binbuf[(size_t)r * CAPB + gpos] = v & 0x00ffffffu;
  }
}

// ---------------------------------------------------------------------------
// scan_local: block b histograms its range's bin segment -> deg, fuses dinv,
// local exclusive scan -> rowrange[i] = (start, end) LOCAL to the range.
// ---------------------------------------------------------------------------
__global__ __launch_bounds__(256) void scan_local_kernel(
    const unsigned* __restrict__ binbuf, const int* __restrict__ bincursor,
    int2* __restrict__ rowrange, float* __restrict__ dinv, int n) {
  __shared__ int deg[256];
  __shared__ int lds[256];
  const int t = threadIdx.x;
  const int b = blockIdx.x;
  deg[t] = 0;
  __syncthreads();
  const int cnt = min(bincursor[b], CAPB);
  const unsigned* seg = binbuf + (size_t)b * CAPB;
  for (int i = t; i < cnt; i += 256) atomicAdd(&deg[(seg[i] >> 16) & 0xff], 1);
  __syncthreads();
  const int i = b * 256 + t;
  int v = deg[t];
  if (i < n) dinv[i] = rsqrtf((float)v + 1.0f);
  lds[t] = v;
  __syncthreads();
#pragma unroll
  for (int o = 1; o < 256; o <<= 1) {
    int u = (t >= o) ? lds[t - o] : 0;
    __syncthreads();
    lds[t] += u;
    __syncthreads();
  }
  if (i < n) rowrange[i] = make_int2(lds[t] - v, lds[t]);
}

// ---------------------------------------------------------------------------
// binB: one block per range; reads contiguous bin segment, computes weights
// (dinv L2-hot), places recs (src | bf16(w)<<16) via LDS cursors, writes
// recs[r*CAPB + local] coalesced.
// ---------------------------------------------------------------------------
__global__ __launch_bounds__(256) void binB_kernel(
    const unsigned* __restrict__ binbuf, const int* __restrict__ bincursor,
    const int2* __restrict__ rowrange, const float* __restrict__ dinv,
    unsigned* __restrict__ recs, int n) {
  __shared__ int curs[256];
  __shared__ unsigned stage[CAPB];
  const int t = threadIdx.x;
  const int r = blockIdx.x;
  const int n0 = r * 256;
  curs[t] = (n0 + t < n) ? rowrange[n0 + t].x : 0;
  __syncthreads();
  const int cnt = min(bincursor[r], CAPB);
  const unsigned* seg = binbuf + (size_t)r * CAPB;
  for (int i = t; i < cnt; i += 256) {
    unsigned v = seg[i];
    int s = v & 0xffffu;
    int dl = (v >> 16) & 0xff;
    float w = dinv[s] * dinv[n0 + dl];
    int pos = atomicAdd(&curs[dl], 1);
    stage[pos] = (unsigned)s | ((unsigned)f2bf(w) << 16);
  }
  __syncthreads();
  unsigned* rout = recs + (size_t)r * CAPB;
  for (int i = t; i < cnt; i += 256) rout[i] = stage[i];
}

// ---------------------------------------------------------------------------
// agg1_gemm2: block = 16 nodes, wave = 2 node-PAIRS x2. Half-wave gather
// with DUAL-NODE interleave: both nodes' 8-deep batches issued in the same
// unrolled loop -> 16 independent row-gathers in flight per half-wave.
// Batch overrun of the shorter node is gated to w=0 (clamped dup loads are
// L1 hits -> cheap). Halves combined via shfl_xor(32); fused gemm2 slab.
// ---------------------------------------------------------------------------
__global__ __launch_bounds__(256) void agg1_gemm2_kernel(
    const unsigned short* __restrict__ h, const unsigned* __restrict__ recs,
    const int2* __restrict__ rowrange, const float* __restrict__ dinv,
    const float* __restrict__ b1, const unsigned short* __restrict__ Wf2,
    unsigned short* __restrict__ h2, int n) {
  __shared__ unsigned short tile[16][136];  // +8 pad; 272B row stride
  const int wave = threadIdx.x >> 6;
  const int lane = threadIdx.x & 63;
  const int sub = lane >> 5;       // half-wave id
  const int c = lane & 31;         // 4 cols per lane: 4c..4c+3
  const int nbase = blockIdx.x * 16;  // N % 16 == 0: all nids valid
  const unsigned* rbase = recs + (size_t)(nbase >> 8) * CAPB;
  const unsigned short* hc = h + c * 4;
  const float4 bv = *(const float4*)(b1 + c * 4);

  for (int qq = 0; qq < 4; qq += 2) {
    const int row0 = wave * 4 + qq;
    const int nid0 = nbase + row0;
    const int nid1 = nid0 + 1;
    const float di0 = dinv[nid0];
    const float di1 = dinv[nid1];
    const int2 rr0 = rowrange[nid0];
    const int2 rr1 = rowrange[nid1];
    const int e0 = rr0.y, e1 = rr1.y;
    const int last0 = (e0 > rr0.x) ? (e0 - 1) : rr0.x;
    const int last1 = (e1 > rr1.x) ? (e1 - 1) : rr1.x;
    const int nb0 = ((e0 - rr0.x) + 15) >> 4;
    const int nb1 = ((e1 - rr1.x) + 15) >> 4;
    const int nb = max(nb0, nb1);
    float a0 = 0.f, a1 = 0.f, a2 = 0.f, a3 = 0.f;
    float g0 = 0.f, g1 = 0.f, g2 = 0.f, g3 = 0.f;
    for (int bt = 0; bt < nb; ++bt) {
      const int pb0 = rr0.x + (bt << 4) + (sub << 3);
      const int pb1 = rr1.x + (bt << 4) + (sub << 3);
#pragma unroll
      for (int j = 0; j < 8; ++j) {
        int ei0 = pb0 + j;
        int ec0 = min(ei0, last0);
        unsigned r0 = rbase[ec0];
        float w0 = (ei0 < e0) ? bf_hi(r0) : 0.f;
        const unsigned* vp0 = (const unsigned*)(hc + (size_t)(r0 & 0xffffu) * 128);
        unsigned u00 = vp0[0];
        unsigned u01 = vp0[1];
        int ei1 = pb1 + j;
        int ec1 = min(ei1, last1);
        unsigned r1 = rbase[ec1];
        float w1 = (ei1 < e1) ? bf_hi(r1) : 0.f;
        const unsigned* vp1 = (const unsigned*)(hc + (size_t)(r1 & 0xffffu) * 128);
        unsigned u10 = vp1[0];
        unsigned u11 = vp1[1];
        a0 += bf_lo(u00) * w0;
        a1 += bf_hi(u00) * w0;
        a2 += bf_lo(u01) * w0;
        a3 += bf_hi(u01) * w0;
        g0 += bf_lo(u10) * w1;
        g1 += bf_hi(u10) * w1;
        g2 += bf_lo(u11) * w1;
        g3 += bf_hi(u11) * w1;
      }
    }
    // combine half-waves (register permute)
    a0 += __shfl_xor(a0, 32, 64);
    a1 += __shfl_xor(a1, 32, 64);
    a2 += __shfl_xor(a2, 32, 64);
    a3 += __shfl_xor(a3, 32, 64);
    g0 += __shfl_xor(g0, 32, 64);
    g1 += __shfl_xor(g1, 32, 64);
    g2 += __shfl_xor(g2, 32, 64);
    g3 += __shfl_xor(g3, 32, 64);
    if (sub == 0) {
      {
        const unsigned* vp = (const unsigned*)(hc + (size_t)nid0 * 128);
        unsigned u0 = vp[0];
        unsigned u1 = vp[1];
        float w2 = di0 * di0;
        a0 = fmaxf(a0 + bf_lo(u0) * w2 + bv.x, 0.f);
        a1 = fmaxf(a1 + bf_hi(u0) * w2 + bv.y, 0.f);
        a2 = fmaxf(a2 + bf_lo(u1) * w2 + bv.z, 0.f);
        a3 = fmaxf(a3 + bf_hi(u1) * w2 + bv.w, 0.f);
        uint2 pk;
        pk.x = ((unsigned)f2bf(a1) << 16) | f2bf(a0);
        pk.y = ((unsigned)f2bf(a3) << 16) | f2bf(a2);
        *(uint2*)&tile[row0][c * 4] = pk;
      }
      {
        const unsigned* vp = (const unsigned*)(hc + (size_t)nid1 * 128);
        unsigned u0 = vp[0];
        unsigned u1 = vp[1];
        float w2 = di1 * di1;
        g0 = fmaxf(g0 + bf_lo(u0) * w2 + bv.x, 0.f);
        g1 = fmaxf(g1 + bf_hi(u0) * w2 + bv.y, 0.f);
        g2 = fmaxf(g2 + bf_lo(u1) * w2 + bv.z, 0.f);
        g3 = fmaxf(g3 + bf_hi(u1) * w2 + bv.w, 0.f);
        uint2 pk;
        pk.x = ((unsigned)f2bf(g1) << 16) | f2bf(g0);
        pk.y = ((unsigned)f2bf(g3) << 16) | f2bf(g2);
        *(uint2*)&tile[row0 + 1][c * 4] = pk;
      }
    }
  }
  __syncthreads();

  const int g = lane >> 4;
  const int m15 = lane & 15;
  f32x4 acc = (f32x4){0.f, 0.f, 0.f, 0.f};
#pragma unroll
  for (int t = 0; t < 4; ++t) {
    bf16x8 af = *(const bf16x8*)&tile[m15][t * 32 + g * 8];
    bf16x8 bf = *(const bf16x8*)(Wf2 + ((size_t)((wave * 4 + t) * 64 + lane)) * 8);
    acc = __builtin_amdgcn_mfma_f32_16x16x32_bf16(af, bf, acc, 0, 0, 0);
  }
#pragma unroll
  for (int r = 0; r < 4; ++r) {
    int row = nbase + g * 4 + r;
    if (row < n) h2[(size_t)row * DOUT + wave * 16 + m15] = f2bf(acc[r]);
  }
}

// ---------------------------------------------------------------------------
// agg2: wave = 2 nodes (dual interleave), block = 8 nodes. Half-wave gather
// of 128B h2 rows (32 lanes x 4B, 2 cols/lane); fp32 out.
// ---------------------------------------------------------------------------
__global__ __launch_bounds__(256) void aggregate2_kernel(
    const unsigned short* __restrict__ h, const unsigned* __restrict__ recs,
    const int2* __restrict__ rowrange, const float* __restrict__ dinv,
    const float* __restrict__ bias, float* __restrict__ out, int n) {
  const int wave = threadIdx.x >> 6;
  const int lane = threadIdx.x & 63;
  const int sub = lane >> 5;
  const int c = lane & 31;  // 2 cols per lane: 2c, 2c+1
  const int nid0 = blockIdx.x * 8 + wave * 2;  // N % 8 == 0: all valid
  const int nid1 = nid0 + 1;

  // nid0 even -> nid0,nid1 always share a 256-range
  const unsigned* rbase = recs + (size_t)(nid0 >> 8) * CAPB;
  const float di0 = dinv[nid0];
  const float di1 = dinv[nid1];
  const int2 rr0 = rowrange[nid0];
  const int2 rr1 = rowrange[nid1];
  const int e0 = rr0.y, e1 = rr1.y;
  const int last0 = (e0 > rr0.x) ? (e0 - 1) : rr0.x;
  const int last1 = (e1 > rr1.x) ? (e1 - 1) : rr1.x;
  const int nb0 = ((e0 - rr0.x) + 15) >> 4;
  const int nb1 = ((e1 - rr1.x) + 15) >> 4;
  const int nb = max(nb0, nb1);
  const unsigned short* hc = h + c * 2;

  float a0 = 0.f, a1 = 0.f, g0 = 0.f, g1 = 0.f;
  for (int bt = 0; bt < nb; ++bt) {
    const int pb0 = rr0.x + (bt << 4) + (sub << 3);
    const int pb1 = rr1.x + (bt << 4) + (sub << 3);
#pragma unroll
    for (int j = 0; j < 8; ++j) {
      int ei0 = pb0 + j;
      int ec0 = min(ei0, last0);
      unsigned r0 = rbase[ec0];
      float w0 = (ei0 < e0) ? bf_hi(r0) : 0.f;
      unsigned v0 = *(const unsigned*)(hc + (size_t)(r0 & 0xffffu) * 64);
      int ei1 = pb1 + j;
      int ec1 = min(ei1, last1);
      unsigned r1 = rbase[ec1];
      float w1 = (ei1 < e1) ? bf_hi(r1) : 0.f;
      unsigned v1 = *(const unsigned*)(hc + (size_t)(r1 & 0xffffu) * 64);
      a0 += bf_lo(v0) * w0;
      a1 += bf_hi(v0) * w0;
      g0 += bf_lo(v1) * w1;
      g1 += bf_hi(v1) * w1;
    }
  }
  a0 += __shfl_xor(a0, 32, 64);
  a1 += __shfl_xor(a1, 32, 64);
  g0 += __shfl_xor(g0, 32, 64);
  g1 += __shfl_xor(g1, 32, 64);
  if (sub == 0) {
    float2 bv = *(const float2*)(bias + c * 2);
    {
      unsigned v = *(const unsigned*)(hc + (size_t)nid0 * 64);
      float w2 = di0 * di0;
      float r0 = fmaxf(a0 + bf_lo(v) * w2 + bv.x, 0.f);
      float r1 = fmaxf(a1 + bf_hi(v) * w2 + bv.y, 0.f);
      *(float2*)(out + (size_t)nid0 * 64 + c * 2) = make_float2(r0, r1);
    }
    {
      unsigned v = *(const unsigned*)(hc + (size_t)nid1 * 64);
      float w2 = di1 * di1;
      float r0 = fmaxf(g0 + bf_lo(v) * w2 + bv.x, 0.f);
      float r1 = fmaxf(g1 + bf_hi(v) * w2 + bv.y, 0.f);
      *(float2*)(out + (size_t)nid1 * 64 + c * 2) = make_float2(r0, r1);
    }
  }
}

// ---------------------------------------------------------------------------
extern "C" void kernel_launch(void* const* d_in, const int* in_sizes, int n_in,
                              void* d_out, int out_size, void* d_ws, size_t ws_size,
                              hipStream_t stream) {
  const float* x = (const float*)d_in[0];
  const int* edge = (const int*)d_in[1];
  const float* W1 = (const float*)d_in[2];
  const float* b1 = (const float*)d_in[3];
  const float* W2 = (const float*)d_in[4];
  const float* b2 = (const float*)d_in[5];
  float* out = (float*)d_out;

  const int N = in_sizes[0] / DIN;   // 50000 (< 65536: src fits in u16)
  const int E = in_sizes[1] / 2;
  const int* src = edge;
  const int* dst = edge + E;
  const int NR = (N + 255) >> 8;              // 196 ranges
  const int nbinA = (E + CHUNK - 1) / CHUNK;  // 196
  const int ntiles1 = (N + 63) / 64;          // 782

  char* base = (char*)d_ws;
  size_t off = 0;
  auto carve = [&](size_t bytes) {
    char* p = base + off;
    off += (bytes + 255) & ~(size_t)255;
    return p;
  };
  float* dinv = (float*)carve((size_t)N * 4);
  int2* rowrange = (int2*)carve((size_t)N * 8);
  int* bincursor = (int*)carve(256 * 4);
  unsigned* binbuf = (unsigned*)carve((size_t)NR * CAPB * 4 + CAPB * 4);
  unsigned* recs = (unsigned*)carve((size_t)NR * CAPB * 4 + 1024);
  unsigned short* h1 = (unsigned short*)carve((size_t)N * DHID * 2);  // bf16
  unsigned short* h2 = (unsigned short*)carve((size_t)N * DOUT * 2);  // bf16
  unsigned short* Wf1 = (unsigned short*)carve((size_t)DIN * DHID * 2);
  unsigned short* Wf2 = (unsigned short*)carve((size_t)DHID * DOUT * 2);

  init_kernel<<<13, 256, 0, stream>>>(W1, W2, Wf1, Wf2, bincursor);
  phaseA_kernel<<<nbinA + ntiles1, 256, 0, stream>>>(
      src, dst, bincursor, binbuf, E, nbinA, x, Wf1, h1, N);
  scan_local_kernel<<<NR, 256, 0, stream>>>(binbuf, bincursor, rowrange, dinv, N);
  binB_kernel<<<NR, 256, 0, stream>>>(binbuf, bincursor, rowrange, dinv, recs, N);
  agg1_gemm2_kernel<<<(N + 15) / 16, 256, 0, stream>>>(
      h1, recs, rowrange, dinv, b1, Wf2, h2, N);
  aggregate2_kernel<<<(N + 7) / 8, 256, 0, stream>>>(
      h2, recs, rowrange, dinv, b2, out, N);
}

// Round 14
// 168.832 us; speedup vs baseline: 1.0442x; 1.0442x over previous
//
#include <hip/hip_runtime.h>

#define DIN 128
#define DHID 128
#define DOUT 64
#define CAPB 6144    // bin capacity per 256-node range (mean ~4082, sigma ~64)
#define CHUNK 4096   // edges per binA block
#define EPT (CHUNK / 256)

typedef short bf16x8 __attribute__((ext_vector_type(8)));
typedef float f32x4 __attribute__((ext_vector_type(4)));

// ---- bf16 helpers ---------------------------------------------------------
static __device__ __forceinline__ unsigned short f2bf(float f) {
  union { float f; unsigned u; } v; v.f = f;
  unsigned r = v.u + 0x7fffu + ((v.u >> 16) & 1u);  // round-nearest-even
  return (unsigned short)(r >> 16);
}
static __device__ __forceinline__ float bf_lo(unsigned v) {
  union { unsigned u; float f; } t; t.u = v << 16; return t.f;
}
static __device__ __forceinline__ float bf_hi(unsigned v) {
  union { unsigned u; float f; } t; t.u = v & 0xffff0000u; return t.f;
}

// ---------------------------------------------------------------------------
// init: zero bincursor + frag-order bf16 conversion of W1/W2 (one launch).
// ---------------------------------------------------------------------------
static __device__ __forceinline__ void wcast_body(
    const float* __restrict__ W, unsigned short* __restrict__ Wf,
    int NOUT, int tid) {
  int f = tid >> 6;
  int lane = tid & 63;
  int t = f & 3;
  int nt = f >> 2;
  int kbase = t * 32 + (lane >> 4) * 8;
  int n = nt * 16 + (lane & 15);
#pragma unroll
  for (int j = 0; j < 8; ++j)
    Wf[(size_t)tid * 8 + j] = f2bf(W[(size_t)(kbase + j) * NOUT + n]);
}

__global__ __launch_bounds__(256) void init_kernel(
    const float* __restrict__ W1, const float* __restrict__ W2,
    unsigned short* __restrict__ Wf1, unsigned short* __restrict__ Wf2,
    int* __restrict__ bincursor) {
  const int b = blockIdx.x;
  const int t = threadIdx.x;
  if (b == 0) {
    bincursor[t] = 0;
  } else if (b <= 8) {
    wcast_body(W1, Wf1, DHID, (b - 1) * 256 + t);
  } else {
    wcast_body(W2, Wf2, DOUT, (b - 9) * 256 + t);
  }
}

// ---------------------------------------------------------------------------
// gemm1 tile: 64 rows of C[M,128](bf16) = A[M,128](fp32) * Wf1 (regs).
// Callable from any dispatch whose blocks have spare capacity — gemm1 work
// is distributed across phaseA / scan_local / binB to fill idle CUs.
// ---------------------------------------------------------------------------
static __device__ void gemm1_tile(
    const float* __restrict__ A, const unsigned short* __restrict__ Wf,
    unsigned short* __restrict__ C, int M, int tile) {
  constexpr int NT = DHID / 16;  // 8
  const int lane = threadIdx.x & 63;
  const int wave = threadIdx.x >> 6;
  const int g = lane >> 4;
  const int m15 = lane & 15;

  bf16x8 bfrag[NT * 4];
#pragma unroll
  for (int f = 0; f < NT * 4; ++f)
    bfrag[f] = *(const bf16x8*)(Wf + ((size_t)(f * 64 + lane)) * 8);

  const int rowbase = tile * 64 + wave * 16;
  if (rowbase >= M) return;
  f32x4 acc[NT];
#pragma unroll
  for (int nt = 0; nt < NT; ++nt) acc[nt] = (f32x4){0.f, 0.f, 0.f, 0.f};
  const float* arow = A + (size_t)(rowbase + m15) * 128 + g * 8;
  bf16x8 af[4];
#pragma unroll
  for (int t = 0; t < 4; ++t) {
    float4 a0 = *(const float4*)(arow + t * 32);
    float4 a1 = *(const float4*)(arow + t * 32 + 4);
    bf16x8 f;
    f[0] = (short)f2bf(a0.x); f[1] = (short)f2bf(a0.y);
    f[2] = (short)f2bf(a0.z); f[3] = (short)f2bf(a0.w);
    f[4] = (short)f2bf(a1.x); f[5] = (short)f2bf(a1.y);
    f[6] = (short)f2bf(a1.z); f[7] = (short)f2bf(a1.w);
    af[t] = f;
  }
#pragma unroll
  for (int t = 0; t < 4; ++t)
#pragma unroll
    for (int nt = 0; nt < NT; ++nt)
      acc[nt] = __builtin_amdgcn_mfma_f32_16x16x32_bf16(
          af[t], bfrag[nt * 4 + t], acc[nt], 0, 0, 0);
#pragma unroll
  for (int nt = 0; nt < NT; ++nt)
#pragma unroll
    for (int r = 0; r < 4; ++r) {
      int row = rowbase + g * 4 + r;
      if (row < M)
        C[(size_t)row * DHID + nt * 16 + m15] = f2bf(acc[nt][r]);
    }
}

// ---------------------------------------------------------------------------
// phaseA: blocks [0,nbinA) bin edges by range (LDS, burst writes); blocks
// [nbinA, ...) each run one gemm1 tile (independent -> overlap).
// ---------------------------------------------------------------------------
__global__ __launch_bounds__(256) void phaseA_kernel(
    const int* __restrict__ src, const int* __restrict__ dst,
    int* __restrict__ bincursor, unsigned* __restrict__ binbuf, int E,
    int nbinA, const float* __restrict__ x,
    const unsigned short* __restrict__ Wf1, unsigned short* __restrict__ h1,
    int M) {
  __shared__ int hist[256];
  __shared__ int cnt[256];
  __shared__ int offs[256];
  __shared__ int cur[256];
  __shared__ int gbase[256];
  __shared__ unsigned stage[CHUNK];

  if ((int)blockIdx.x >= nbinA) {
    gemm1_tile(x, Wf1, h1, M, (int)blockIdx.x - nbinA);
    return;
  }

  const int t = threadIdx.x;
  const int base = blockIdx.x * CHUNK;
  const int n = min(CHUNK, E - base);

  hist[t] = 0;
  __syncthreads();

  unsigned rec[EPT];
  int rng[EPT];
#pragma unroll
  for (int j = 0; j < EPT; ++j) {
    int e = base + j * 256 + t;
    rng[j] = -1;
    if (e < E) {
      int d = dst[e];
      int s = src[e];
      int r = d >> 8;
      rng[j] = r;
      rec[j] = (unsigned)s | ((unsigned)(d & 255) << 16) | ((unsigned)r << 24);
      atomicAdd(&hist[r], 1);
    }
  }
  __syncthreads();
  int myc = hist[t];
  cnt[t] = myc;
  __syncthreads();
#pragma unroll
  for (int o = 1; o < 256; o <<= 1) {
    int u = (t >= o) ? hist[t - o] : 0;
    __syncthreads();
    hist[t] += u;
    __syncthreads();
  }
  offs[t] = hist[t] - myc;
  cur[t] = hist[t] - myc;
  __syncthreads();
#pragma unroll
  for (int j = 0; j < EPT; ++j) {
    if (rng[j] >= 0) {
      int pos = atomicAdd(&cur[rng[j]], 1);
      stage[pos] = rec[j];
    }
  }
  __syncthreads();
  int c = cnt[t];
  gbase[t] = c ? atomicAdd(&bincursor[t], c) : 0;
  __syncthreads();
  for (int i = t; i < n; i += 256) {
    unsigned v = stage[i];
    int r = v >> 24;
    int local = i - offs[r];
    int gpos = gbase[r] + local;
    if (gpos < CAPB) binbuf[(size_t)r * CAPB + gpos] = v & 0x00ffffffu;
  }
}

// ---------------------------------------------------------------------------
// scan_local: blocks [0,NR) histogram their range's bin segment -> deg,
// fuse dinv, local exclusive scan -> rowrange (start,end local to range).
// Blocks [NR,...) run gemm1 tiles (fills the otherwise ~idle machine).
// ---------------------------------------------------------------------------
__global__ __launch_bounds__(256) void scan_local_kernel(
    const unsigned* __restrict__ binbuf, const int* __restrict__ bincursor,
    int2* __restrict__ rowrange, float* __restrict__ dinv, int n, int nscan,
    const float* __restrict__ x, const unsigned short* __restrict__ Wf1,
    unsigned short* __restrict__ h1, int M, int tilebase) {
  __shared__ int deg[256];
  __shared__ int lds[256];
  if ((int)blockIdx.x >= nscan) {
    gemm1_tile(x, Wf1, h1, M, tilebase + (int)blockIdx.x - nscan);
    return;
  }
  const int t = threadIdx.x;
  const int b = blockIdx.x;
  deg[t] = 0;
  __syncthreads();
  const int cnt = min(bincursor[b], CAPB);
  const unsigned* seg = binbuf + (size_t)b * CAPB;
  for (int i = t; i < cnt; i += 256) atomicAdd(&deg[(seg[i] >> 16) & 0xff], 1);
  __syncthreads();
  const int i = b * 256 + t;
  int v = deg[t];
  if (i < n) dinv[i] = rsqrtf((float)v + 1.0f);
  lds[t] = v;
  __syncthreads();
#pragma unroll
  for (int o = 1; o < 256; o <<= 1) {
    int u = (t >= o) ? lds[t - o] : 0;
    __syncthreads();
    lds[t] += u;
    __syncthreads();
  }
  if (i < n) rowrange[i] = make_int2(lds[t] - v, lds[t]);
}

// ---------------------------------------------------------------------------
// binB: blocks [0,NR) read their contiguous bin segment, compute weights
// (dinv L2-hot), place recs (src | bf16(w)<<16) via LDS cursors, write
// recs[r*CAPB + local] coalesced. Blocks [NR,...) run gemm1 tiles.
// ---------------------------------------------------------------------------
__global__ __launch_bounds__(256) void binB_kernel(
    const unsigned* __restrict__ binbuf, const int* __restrict__ bincursor,
    const int2* __restrict__ rowrange, const float* __restrict__ dinv,
    unsigned* __restrict__ recs, int n, int nbinB,
    const float* __restrict__ x, const unsigned short* __restrict__ Wf1,
    unsigned short* __restrict__ h1, int M, int tilebase) {
  __shared__ int curs[256];
  __shared__ unsigned stage[CAPB];
  if ((int)blockIdx.x >= nbinB) {
    gemm1_tile(x, Wf1, h1, M, tilebase + (int)blockIdx.x - nbinB);
    return;
  }
  const int t = threadIdx.x;
  const int r = blockIdx.x;
  const int n0 = r * 256;
  curs[t] = (n0 + t < n) ? rowrange[n0 + t].x : 0;
  __syncthreads();
  const int cnt = min(bincursor[r], CAPB);
  const unsigned* seg = binbuf + (size_t)r * CAPB;
  for (int i = t; i < cnt; i += 256) {
    unsigned v = seg[i];
    int s = v & 0xffffu;
    int dl = (v >> 16) & 0xff;
    float w = dinv[s] * dinv[n0 + dl];
    int pos = atomicAdd(&curs[dl], 1);
    stage[pos] = (unsigned)s | ((unsigned)f2bf(w) << 16);
  }
  __syncthreads();
  unsigned* rout = recs + (size_t)r * CAPB;
  for (int i = t; i < cnt; i += 256) rout[i] = stage[i];
}

// ---------------------------------------------------------------------------
// agg1_gemm2 (round-12 known-good form): block = 16 nodes, wave = 4 nodes.
// Half-wave gather: lanes 0-31 fetch edge A's 256B h1 row (8B/lane), lanes
// 32-63 edge B's; 8-deep clamped batches = 16 rows in flight. Halves
// combined via shfl_xor(32); fused gemm2 slab epilogue.
// ---------------------------------------------------------------------------
__global__ __launch_bounds__(256) void agg1_gemm2_kernel(
    const unsigned short* __restrict__ h, const unsigned* __restrict__ recs,
    const int2* __restrict__ rowrange, const float* __restrict__ dinv,
    const float* __restrict__ b1, const unsigned short* __restrict__ Wf2,
    unsigned short* __restrict__ h2, int n) {
  __shared__ unsigned short tile[16][136];  // +8 pad; 272B row stride
  const int wave = threadIdx.x >> 6;
  const int lane = threadIdx.x & 63;
  const int sub = lane >> 5;       // half-wave id
  const int c = lane & 31;         // 4 cols per lane: 4c..4c+3
  const int nbase = blockIdx.x * 16;
  const unsigned* rbase = recs + (size_t)(nbase >> 8) * CAPB;
  const unsigned short* hc = h + c * 4;

  for (int q = 0; q < 4; ++q) {
    const int row = wave * 4 + q;
    const int nid = nbase + row;
    if (nid >= n) break;
    const float di = dinv[nid];
    const int2 rr = rowrange[nid];
    const int p0 = rr.x;
    const int end = rr.y;
    const int d = end - p0;
    float a0 = 0.f, a1 = 0.f, a2 = 0.f, a3 = 0.f;
    const int nb = (d + 15) >> 4;
    for (int b = 0; b < nb; ++b) {
      const int pb = p0 + (b << 4) + (sub << 3);
#pragma unroll
      for (int j = 0; j < 8; ++j) {
        int ei = pb + j;
        int ec = min(ei, end - 1);
        unsigned r = rbase[ec];
        float w = (ei < end) ? bf_hi(r) : 0.f;
        const unsigned* vp = (const unsigned*)(hc + (size_t)(r & 0xffffu) * 128);
        unsigned u0 = vp[0];
        unsigned u1 = vp[1];
        a0 += bf_lo(u0) * w;
        a1 += bf_hi(u0) * w;
        a2 += bf_lo(u1) * w;
        a3 += bf_hi(u1) * w;
      }
    }
    // combine half-waves (register permute)
    a0 += __shfl_xor(a0, 32, 64);
    a1 += __shfl_xor(a1, 32, 64);
    a2 += __shfl_xor(a2, 32, 64);
    a3 += __shfl_xor(a3, 32, 64);
    if (sub == 0) {
      const unsigned* vp = (const unsigned*)(hc + (size_t)nid * 128);
      unsigned u0 = vp[0];
      unsigned u1 = vp[1];
      float w2 = di * di;
      a0 += bf_lo(u0) * w2;
      a1 += bf_hi(u0) * w2;
      a2 += bf_lo(u1) * w2;
      a3 += bf_hi(u1) * w2;
      float4 bv = *(const float4*)(b1 + c * 4);
      a0 = fmaxf(a0 + bv.x, 0.f);
      a1 = fmaxf(a1 + bv.y, 0.f);
      a2 = fmaxf(a2 + bv.z, 0.f);
      a3 = fmaxf(a3 + bv.w, 0.f);
      uint2 pk;
      pk.x = ((unsigned)f2bf(a1) << 16) | f2bf(a0);
      pk.y = ((unsigned)f2bf(a3) << 16) | f2bf(a2);
      *(uint2*)&tile[row][c * 4] = pk;
    }
  }
  __syncthreads();

  const int g = lane >> 4;
  const int m15 = lane & 15;
  f32x4 acc = (f32x4){0.f, 0.f, 0.f, 0.f};
#pragma unroll
  for (int t = 0; t < 4; ++t) {
    bf16x8 af = *(const bf16x8*)&tile[m15][t * 32 + g * 8];
    bf16x8 bf = *(const bf16x8*)(Wf2 + ((size_t)((wave * 4 + t) * 64 + lane)) * 8);
    acc = __builtin_amdgcn_mfma_f32_16x16x32_bf16(af, bf, acc, 0, 0, 0);
  }
#pragma unroll
  for (int r = 0; r < 4; ++r) {
    int row = nbase + g * 4 + r;
    if (row < n) h2[(size_t)row * DOUT + wave * 16 + m15] = f2bf(acc[r]);
  }
}

// ---------------------------------------------------------------------------
// agg2 (round-12 known-good form): one wave per node; half-wave gather
// (128B h2 row = 32 lanes x 4B, 2 cols/lane), clamped 8-deep batches.
// ---------------------------------------------------------------------------
__global__ __launch_bounds__(256) void aggregate2_kernel(
    const unsigned short* __restrict__ h, const unsigned* __restrict__ recs,
    const int2* __restrict__ rowrange, const float* __restrict__ dinv,
    const float* __restrict__ bias, float* __restrict__ out, int n) {
  const int wave = threadIdx.x >> 6;
  const int lane = threadIdx.x & 63;
  const int sub = lane >> 5;
  const int c = lane & 31;  // 2 cols per lane: 2c, 2c+1
  const int nid = blockIdx.x * 4 + wave;
  if (nid >= n) return;

  const unsigned* rbase = recs + (size_t)(nid >> 8) * CAPB;
  const float di = dinv[nid];
  const int2 rr = rowrange[nid];
  const int p0 = rr.x;
  const int end = rr.y;
  const int d = end - p0;
  const unsigned short* hc = h + c * 2;

  float a0 = 0.f, a1 = 0.f;
  const int nb = (d + 15) >> 4;
  for (int b = 0; b < nb; ++b) {
    const int pb = p0 + (b << 4) + (sub << 3);
#pragma unroll
    for (int j = 0; j < 8; ++j) {
      int ei = pb + j;
      int ec = min(ei, end - 1);
      unsigned r = rbase[ec];
      float w = (ei < end) ? bf_hi(r) : 0.f;
      unsigned v = *(const unsigned*)(hc + (size_t)(r & 0xffffu) * 64);
      a0 += bf_lo(v) * w;
      a1 += bf_hi(v) * w;
    }
  }
  a0 += __shfl_xor(a0, 32, 64);
  a1 += __shfl_xor(a1, 32, 64);
  if (sub == 0) {
    unsigned v = *(const unsigned*)(hc + (size_t)nid * 64);
    float w2 = di * di;
    a0 += bf_lo(v) * w2;
    a1 += bf_hi(v) * w2;
    float2 bv = *(const float2*)(bias + c * 2);
    a0 = fmaxf(a0 + bv.x, 0.f);
    a1 = fmaxf(a1 + bv.y, 0.f);
    *(float2*)(out + (size_t)nid * 64 + c * 2) = make_float2(a0, a1);
  }
}

// ---------------------------------------------------------------------------
extern "C" void kernel_launch(void* const* d_in, const int* in_sizes, int n_in,
                              void* d_out, int out_size, void* d_ws, size_t ws_size,
                              hipStream_t stream) {
  const float* x = (const float*)d_in[0];
  const int* edge = (const int*)d_in[1];
  const float* W1 = (const float*)d_in[2];
  const float* b1 = (const float*)d_in[3];
  const float* W2 = (const float*)d_in[4];
  const float* b2 = (const float*)d_in[5];
  float* out = (float*)d_out;

  const int N = in_sizes[0] / DIN;   // 50000 (< 65536: src fits in u16)
  const int E = in_sizes[1] / 2;
  const int* src = edge;
  const int* dst = edge + E;
  const int NR = (N + 255) >> 8;              // 196 ranges
  const int nbinA = (E + CHUNK - 1) / CHUNK;  // 196
  const int ntiles1 = (N + 63) / 64;          // 782 gemm1 tiles

  // distribute gemm1 tiles: phaseA gets TA, scan_local TS, binB the rest
  const int TS = NR;                   // 196 tiles hidden behind scan
  const int TB = NR;                   // 196 tiles hidden behind binB
  const int TA = ntiles1 - TS - TB;    // 390 tiles in phaseA

  char* base = (char*)d_ws;
  size_t off = 0;
  auto carve = [&](size_t bytes) {
    char* p = base + off;
    off += (bytes + 255) & ~(size_t)255;
    return p;
  };
  float* dinv = (float*)carve((size_t)N * 4);
  int2* rowrange = (int2*)carve((size_t)N * 8);
  int* bincursor = (int*)carve(256 * 4);
  unsigned* binbuf = (unsigned*)carve((size_t)NR * CAPB * 4 + CAPB * 4);
  unsigned* recs = (unsigned*)carve((size_t)NR * CAPB * 4 + 1024);
  unsigned short* h1 = (unsigned short*)carve((size_t)N * DHID * 2);  // bf16
  unsigned short* h2 = (unsigned short*)carve((size_t)N * DOUT * 2);  // bf16
  unsigned short* Wf1 = (unsigned short*)carve((size_t)DIN * DHID * 2);
  unsigned short* Wf2 = (unsigned short*)carve((size_t)DHID * DOUT * 2);

  init_kernel<<<13, 256, 0, stream>>>(W1, W2, Wf1, Wf2, bincursor);
  phaseA_kernel<<<nbinA + TA, 256, 0, stream>>>(
      src, dst, bincursor, binbuf, E, nbinA, x, Wf1, h1, N);
  scan_local_kernel<<<NR + TS, 256, 0, stream>>>(
      binbuf, bincursor, rowrange, dinv, N, NR, x, Wf1, h1, N, TA);
  binB_kernel<<<NR + TB, 256, 0, stream>>>(
      binbuf, bincursor, rowrange, dinv, recs, N, NR, x, Wf1, h1, N, TA + TS);
  agg1_gemm2_kernel<<<(N + 15) / 16, 256, 0, stream>>>(
      h1, recs, rowrange, dinv, b1, Wf2, h2, N);
  aggregate2_kernel<<<(N + 3) / 4, 256, 0, stream>>>(
      h2, recs, rowrange, dinv, b2, out, N);
}

// Round 15
// 162.974 us; speedup vs baseline: 1.0817x; 1.0359x over previous
//
#include <hip/hip_runtime.h>

#define DIN 128
#define DHID 128
#define DOUT 64
#define CAPB 6144    // bin capacity per 256-node range (mean ~4082, sigma ~64)
#define CHUNK 4096   // edges per binA block
#define EPT (CHUNK / 256)

typedef short bf16x8 __attribute__((ext_vector_type(8)));
typedef float f32x4 __attribute__((ext_vector_type(4)));

// ---- bf16 helpers ---------------------------------------------------------
static __device__ __forceinline__ unsigned short f2bf(float f) {
  union { float f; unsigned u; } v; v.f = f;
  unsigned r = v.u + 0x7fffu + ((v.u >> 16) & 1u);  // round-nearest-even
  return (unsigned short)(r >> 16);
}
static __device__ __forceinline__ float bf_lo(unsigned v) {
  union { unsigned u; float f; } t; t.u = v << 16; return t.f;
}
static __device__ __forceinline__ float bf_hi(unsigned v) {
  union { unsigned u; float f; } t; t.u = v & 0xffff0000u; return t.f;
}

// ---------------------------------------------------------------------------
// init: zero bincursor + frag-order bf16 conversion of W1/W2 (one launch).
// ---------------------------------------------------------------------------
static __device__ __forceinline__ void wcast_body(
    const float* __restrict__ W, unsigned short* __restrict__ Wf,
    int NOUT, int tid) {
  int f = tid >> 6;
  int lane = tid & 63;
  int t = f & 3;
  int nt = f >> 2;
  int kbase = t * 32 + (lane >> 4) * 8;
  int n = nt * 16 + (lane & 15);
#pragma unroll
  for (int j = 0; j < 8; ++j)
    Wf[(size_t)tid * 8 + j] = f2bf(W[(size_t)(kbase + j) * NOUT + n]);
}

__global__ __launch_bounds__(256) void init_kernel(
    const float* __restrict__ W1, const float* __restrict__ W2,
    unsigned short* __restrict__ Wf1, unsigned short* __restrict__ Wf2,
    int* __restrict__ bincursor) {
  const int b = blockIdx.x;
  const int t = threadIdx.x;
  if (b == 0) {
    bincursor[t] = 0;
  } else if (b <= 8) {
    wcast_body(W1, Wf1, DHID, (b - 1) * 256 + t);
  } else {
    wcast_body(W2, Wf2, DOUT, (b - 9) * 256 + t);
  }
}

// ---------------------------------------------------------------------------
// gemm1 tile: 64 rows of C[M,128](bf16) = A[M,128](fp32) * Wf1 (regs).
// ---------------------------------------------------------------------------
static __device__ void gemm1_tile(
    const float* __restrict__ A, const unsigned short* __restrict__ Wf,
    unsigned short* __restrict__ C, int M, int tile) {
  constexpr int NT = DHID / 16;  // 8
  const int lane = threadIdx.x & 63;
  const int wave = threadIdx.x >> 6;
  const int g = lane >> 4;
  const int m15 = lane & 15;

  bf16x8 bfrag[NT * 4];
#pragma unroll
  for (int f = 0; f < NT * 4; ++f)
    bfrag[f] = *(const bf16x8*)(Wf + ((size_t)(f * 64 + lane)) * 8);

  const int rowbase = tile * 64 + wave * 16;
  if (rowbase >= M) return;
  f32x4 acc[NT];
#pragma unroll
  for (int nt = 0; nt < NT; ++nt) acc[nt] = (f32x4){0.f, 0.f, 0.f, 0.f};
  const float* arow = A + (size_t)(rowbase + m15) * 128 + g * 8;
  bf16x8 af[4];
#pragma unroll
  for (int t = 0; t < 4; ++t) {
    float4 a0 = *(const float4*)(arow + t * 32);
    float4 a1 = *(const float4*)(arow + t * 32 + 4);
    bf16x8 f;
    f[0] = (short)f2bf(a0.x); f[1] = (short)f2bf(a0.y);
    f[2] = (short)f2bf(a0.z); f[3] = (short)f2bf(a0.w);
    f[4] = (short)f2bf(a1.x); f[5] = (short)f2bf(a1.y);
    f[6] = (short)f2bf(a1.z); f[7] = (short)f2bf(a1.w);
    af[t] = f;
  }
#pragma unroll
  for (int t = 0; t < 4; ++t)
#pragma unroll
    for (int nt = 0; nt < NT; ++nt)
      acc[nt] = __builtin_amdgcn_mfma_f32_16x16x32_bf16(
          af[t], bfrag[nt * 4 + t], acc[nt], 0, 0, 0);
#pragma unroll
  for (int nt = 0; nt < NT; ++nt)
#pragma unroll
    for (int r = 0; r < 4; ++r) {
      int row = rowbase + g * 4 + r;
      if (row < M)
        C[(size_t)row * DHID + nt * 16 + m15] = f2bf(acc[nt][r]);
    }
}

// ---------------------------------------------------------------------------
// phaseA: blocks [0,nbinA) bin edges by range (LDS, burst writes); blocks
// [nbinA, ...) each run one gemm1 tile (independent -> overlap).
// ---------------------------------------------------------------------------
__global__ __launch_bounds__(256) void phaseA_kernel(
    const int* __restrict__ src, const int* __restrict__ dst,
    int* __restrict__ bincursor, unsigned* __restrict__ binbuf, int E,
    int nbinA, const float* __restrict__ x,
    const unsigned short* __restrict__ Wf1, unsigned short* __restrict__ h1,
    int M) {
  __shared__ int hist[256];
  __shared__ int cnt[256];
  __shared__ int offs[256];
  __shared__ int cur[256];
  __shared__ int gbase[256];
  __shared__ unsigned stage[CHUNK];

  if ((int)blockIdx.x >= nbinA) {
    gemm1_tile(x, Wf1, h1, M, (int)blockIdx.x - nbinA);
    return;
  }

  const int t = threadIdx.x;
  const int base = blockIdx.x * CHUNK;
  const int n = min(CHUNK, E - base);

  hist[t] = 0;
  __syncthreads();

  unsigned rec[EPT];
  int rng[EPT];
#pragma unroll
  for (int j = 0; j < EPT; ++j) {
    int e = base + j * 256 + t;
    rng[j] = -1;
    if (e < E) {
      int d = dst[e];
      int s = src[e];
      int r = d >> 8;
      rng[j] = r;
      rec[j] = (unsigned)s | ((unsigned)(d & 255) << 16) | ((unsigned)r << 24);
      atomicAdd(&hist[r], 1);
    }
  }
  __syncthreads();
  int myc = hist[t];
  cnt[t] = myc;
  __syncthreads();
#pragma unroll
  for (int o = 1; o < 256; o <<= 1) {
    int u = (t >= o) ? hist[t - o] : 0;
    __syncthreads();
    hist[t] += u;
    __syncthreads();
  }
  offs[t] = hist[t] - myc;
  cur[t] = hist[t] - myc;
  __syncthreads();
#pragma unroll
  for (int j = 0; j < EPT; ++j) {
    if (rng[j] >= 0) {
      int pos = atomicAdd(&cur[rng[j]], 1);
      stage[pos] = rec[j];
    }
  }
  __syncthreads();
  int c = cnt[t];
  gbase[t] = c ? atomicAdd(&bincursor[t], c) : 0;
  __syncthreads();
  for (int i = t; i < n; i += 256) {
    unsigned v = stage[i];
    int r = v >> 24;
    int local = i - offs[r];
    int gpos = gbase[r] + local;
    if (gpos < CAPB) binbuf[(size_t)r * CAPB + gpos] = v & 0x00ffffffu;
  }
}

// ---------------------------------------------------------------------------
// scan_local: block b histograms its range's bin segment -> deg, fuses dinv,
// local exclusive scan -> rowrange[i] = (start, end) LOCAL to the range.
// ---------------------------------------------------------------------------
__global__ __launch_bounds__(256) void scan_local_kernel(
    const unsigned* __restrict__ binbuf, const int* __restrict__ bincursor,
    int2* __restrict__ rowrange, float* __restrict__ dinv, int n) {
  __shared__ int deg[256];
  __shared__ int lds[256];
  const int t = threadIdx.x;
  const int b = blockIdx.x;
  deg[t] = 0;
  __syncthreads();
  const int cnt = min(bincursor[b], CAPB);
  const unsigned* seg = binbuf + (size_t)b * CAPB;
  for (int i = t; i < cnt; i += 256) atomicAdd(&deg[(seg[i] >> 16) & 0xff], 1);
  __syncthreads();
  const int i = b * 256 + t;
  int v = deg[t];
  if (i < n) dinv[i] = rsqrtf((float)v + 1.0f);
  lds[t] = v;
  __syncthreads();
#pragma unroll
  for (int o = 1; o < 256; o <<= 1) {
    int u = (t >= o) ? lds[t - o] : 0;
    __syncthreads();
    lds[t] += u;
    __syncthreads();
  }
  if (i < n) rowrange[i] = make_int2(lds[t] - v, lds[t]);
}

// ---------------------------------------------------------------------------
// binB: one block per range; reads contiguous bin segment, computes weights
// (dinv L2-hot), places recs (src | bf16(w)<<16) via LDS cursors, writes
// recs[r*CAPB + local] coalesced.
// ---------------------------------------------------------------------------
__global__ __launch_bounds__(256) void binB_kernel(
    const unsigned* __restrict__ binbuf, const int* __restrict__ bincursor,
    const int2* __restrict__ rowrange, const float* __restrict__ dinv,
    unsigned* __restrict__ recs, int n) {
  __shared__ int curs[256];
  __shared__ unsigned stage[CAPB];
  const int t = threadIdx.x;
  const int r = blockIdx.x;
  const int n0 = r * 256;
  curs[t] = (n0 + t < n) ? rowrange[n0 + t].x : 0;
  __syncthreads();
  const int cnt = min(bincursor[r], CAPB);
  const unsigned* seg = binbuf + (size_t)r * CAPB;
  for (int i = t; i < cnt; i += 256) {
    unsigned v = seg[i];
    int s = v & 0xffffu;
    int dl = (v >> 16) & 0xff;
    float w = dinv[s] * dinv[n0 + dl];
    int pos = atomicAdd(&curs[dl], 1);
    stage[pos] = (unsigned)s | ((unsigned)f2bf(w) << 16);
  }
  __syncthreads();
  unsigned* rout = recs + (size_t)r * CAPB;
  for (int i = t; i < cnt; i += 256) rout[i] = stage[i];
}

// ---------------------------------------------------------------------------
// agg1_gemm2: block = 16 nodes, wave = 4 nodes. QUARTER-WAVE gather: each
// 16-lane quarter fetches one edge's full 256B h1 row as uint4 (16B/lane,
// coalescing sweet spot) -> 4 edges per j-step, 4 j-steps per 16-edge batch
// (half the issued instructions of the half-wave form at the same 16-chain
// MLP). Clamped tails (dup loads = L1 hits). Reduce via xor16+xor32; fused
// gemm2 slab epilogue.
// ---------------------------------------------------------------------------
__global__ __launch_bounds__(256) void agg1_gemm2_kernel(
    const unsigned short* __restrict__ h, const unsigned* __restrict__ recs,
    const int2* __restrict__ rowrange, const float* __restrict__ dinv,
    const float* __restrict__ b1, const unsigned short* __restrict__ Wf2,
    unsigned short* __restrict__ h2, int n) {
  __shared__ unsigned short tile[16][136];  // +8 pad; 272B row stride
  const int wave = threadIdx.x >> 6;
  const int lane = threadIdx.x & 63;
  const int qt = lane >> 4;        // quarter id 0..3 (edge slot within j)
  const int li = lane & 15;        // cols 8*li .. 8*li+7 (16B per lane)
  const int nbase = blockIdx.x * 16;
  const unsigned* rbase = recs + (size_t)(nbase >> 8) * CAPB;
  const unsigned short* hc = h + li * 8;

  for (int q = 0; q < 4; ++q) {
    const int row = wave * 4 + q;
    const int nid = nbase + row;
    if (nid >= n) break;
    const float di = dinv[nid];
    const int2 rr = rowrange[nid];
    const int p0 = rr.x;
    const int end = rr.y;
    const int d = end - p0;
    const int last = (d > 0) ? (end - 1) : p0;
    float a0 = 0.f, a1 = 0.f, a2 = 0.f, a3 = 0.f;
    float a4 = 0.f, a5 = 0.f, a6 = 0.f, a7 = 0.f;
    const int nb = (d + 15) >> 4;
    for (int bt = 0; bt < nb; ++bt) {
      const int pb = p0 + (bt << 4) + qt;
#pragma unroll
      for (int j = 0; j < 4; ++j) {
        int ei = pb + j * 4;
        int ec = min(ei, last);
        unsigned r = rbase[ec];
        float w = (ei < end) ? bf_hi(r) : 0.f;
        uint4 u = *(const uint4*)(hc + (size_t)(r & 0xffffu) * 128);
        a0 += bf_lo(u.x) * w;
        a1 += bf_hi(u.x) * w;
        a2 += bf_lo(u.y) * w;
        a3 += bf_hi(u.y) * w;
        a4 += bf_lo(u.z) * w;
        a5 += bf_hi(u.z) * w;
        a6 += bf_lo(u.w) * w;
        a7 += bf_hi(u.w) * w;
      }
    }
    // combine quarters (register permutes)
    a0 += __shfl_xor(a0, 16, 64); a0 += __shfl_xor(a0, 32, 64);
    a1 += __shfl_xor(a1, 16, 64); a1 += __shfl_xor(a1, 32, 64);
    a2 += __shfl_xor(a2, 16, 64); a2 += __shfl_xor(a2, 32, 64);
    a3 += __shfl_xor(a3, 16, 64); a3 += __shfl_xor(a3, 32, 64);
    a4 += __shfl_xor(a4, 16, 64); a4 += __shfl_xor(a4, 32, 64);
    a5 += __shfl_xor(a5, 16, 64); a5 += __shfl_xor(a5, 32, 64);
    a6 += __shfl_xor(a6, 16, 64); a6 += __shfl_xor(a6, 32, 64);
    a7 += __shfl_xor(a7, 16, 64); a7 += __shfl_xor(a7, 32, 64);
    if (qt == 0) {
      uint4 u = *(const uint4*)(hc + (size_t)nid * 128);
      float w2 = di * di;
      a0 += bf_lo(u.x) * w2;
      a1 += bf_hi(u.x) * w2;
      a2 += bf_lo(u.y) * w2;
      a3 += bf_hi(u.y) * w2;
      a4 += bf_lo(u.z) * w2;
      a5 += bf_hi(u.z) * w2;
      a6 += bf_lo(u.w) * w2;
      a7 += bf_hi(u.w) * w2;
      float4 bv0 = *(const float4*)(b1 + li * 8);
      float4 bv1 = *(const float4*)(b1 + li * 8 + 4);
      a0 = fmaxf(a0 + bv0.x, 0.f);
      a1 = fmaxf(a1 + bv0.y, 0.f);
      a2 = fmaxf(a2 + bv0.z, 0.f);
      a3 = fmaxf(a3 + bv0.w, 0.f);
      a4 = fmaxf(a4 + bv1.x, 0.f);
      a5 = fmaxf(a5 + bv1.y, 0.f);
      a6 = fmaxf(a6 + bv1.z, 0.f);
      a7 = fmaxf(a7 + bv1.w, 0.f);
      uint4 pk;
      pk.x = ((unsigned)f2bf(a1) << 16) | f2bf(a0);
      pk.y = ((unsigned)f2bf(a3) << 16) | f2bf(a2);
      pk.z = ((unsigned)f2bf(a5) << 16) | f2bf(a4);
      pk.w = ((unsigned)f2bf(a7) << 16) | f2bf(a6);
      *(uint4*)&tile[row][li * 8] = pk;
    }
  }
  __syncthreads();

  const int g = lane >> 4;
  const int m15 = lane & 15;
  f32x4 acc = (f32x4){0.f, 0.f, 0.f, 0.f};
#pragma unroll
  for (int t = 0; t < 4; ++t) {
    bf16x8 af = *(const bf16x8*)&tile[m15][t * 32 + g * 8];
    bf16x8 bf = *(const bf16x8*)(Wf2 + ((size_t)((wave * 4 + t) * 64 + lane)) * 8);
    acc = __builtin_amdgcn_mfma_f32_16x16x32_bf16(af, bf, acc, 0, 0, 0);
  }
#pragma unroll
  for (int r = 0; r < 4; ++r) {
    int row = nbase + g * 4 + r;
    if (row < n) h2[(size_t)row * DOUT + wave * 16 + m15] = f2bf(acc[r]);
  }
}

// ---------------------------------------------------------------------------
// agg2: one wave per node; QUARTER-WAVE gather of 128B h2 rows (16 lanes x
// 8B uint2, 4 cols/lane) -> 4 edges per j-step; clamped batches; fp32 out.
// ---------------------------------------------------------------------------
__global__ __launch_bounds__(256) void aggregate2_kernel(
    const unsigned short* __restrict__ h, const unsigned* __restrict__ recs,
    const int2* __restrict__ rowrange, const float* __restrict__ dinv,
    const float* __restrict__ bias, float* __restrict__ out, int n) {
  const int wave = threadIdx.x >> 6;
  const int lane = threadIdx.x & 63;
  const int qt = lane >> 4;
  const int li = lane & 15;  // cols 4*li .. 4*li+3
  const int nid = blockIdx.x * 4 + wave;
  if (nid >= n) return;

  const unsigned* rbase = recs + (size_t)(nid >> 8) * CAPB;
  const float di = dinv[nid];
  const int2 rr = rowrange[nid];
  const int p0 = rr.x;
  const int end = rr.y;
  const int d = end - p0;
  const int last = (d > 0) ? (end - 1) : p0;
  const unsigned short* hc = h + li * 4;

  float a0 = 0.f, a1 = 0.f, a2 = 0.f, a3 = 0.f;
  const int nb = (d + 15) >> 4;
  for (int bt = 0; bt < nb; ++bt) {
    const int pb = p0 + (bt << 4) + qt;
#pragma unroll
    for (int j = 0; j < 4; ++j) {
      int ei = pb + j * 4;
      int ec = min(ei, last);
      unsigned r = rbase[ec];
      float w = (ei < end) ? bf_hi(r) : 0.f;
      uint2 u = *(const uint2*)(hc + (size_t)(r & 0xffffu) * 64);
      a0 += bf_lo(u.x) * w;
      a1 += bf_hi(u.x) * w;
      a2 += bf_lo(u.y) * w;
      a3 += bf_hi(u.y) * w;
    }
  }
  a0 += __shfl_xor(a0, 16, 64); a0 += __shfl_xor(a0, 32, 64);
  a1 += __shfl_xor(a1, 16, 64); a1 += __shfl_xor(a1, 32, 64);
  a2 += __shfl_xor(a2, 16, 64); a2 += __shfl_xor(a2, 32, 64);
  a3 += __shfl_xor(a3, 16, 64); a3 += __shfl_xor(a3, 32, 64);
  if (qt == 0) {
    uint2 u = *(const uint2*)(hc + (size_t)nid * 64);
    float w2 = di * di;
    a0 += bf_lo(u.x) * w2;
    a1 += bf_hi(u.x) * w2;
    a2 += bf_lo(u.y) * w2;
    a3 += bf_hi(u.y) * w2;
    float4 bv = *(const float4*)(bias + li * 4);
    a0 = fmaxf(a0 + bv.x, 0.f);
    a1 = fmaxf(a1 + bv.y, 0.f);
    a2 = fmaxf(a2 + bv.z, 0.f);
    a3 = fmaxf(a3 + bv.w, 0.f);
    *(float4*)(out + (size_t)nid * 64 + li * 4) = make_float4(a0, a1, a2, a3);
  }
}

// ---------------------------------------------------------------------------
extern "C" void kernel_launch(void* const* d_in, const int* in_sizes, int n_in,
                              void* d_out, int out_size, void* d_ws, size_t ws_size,
                              hipStream_t stream) {
  const float* x = (const float*)d_in[0];
  const int* edge = (const int*)d_in[1];
  const float* W1 = (const float*)d_in[2];
  const float* b1 = (const float*)d_in[3];
  const float* W2 = (const float*)d_in[4];
  const float* b2 = (const float*)d_in[5];
  float* out = (float*)d_out;

  const int N = in_sizes[0] / DIN;   // 50000 (< 65536: src fits in u16)
  const int E = in_sizes[1] / 2;
  const int* src = edge;
  const int* dst = edge + E;
  const int NR = (N + 255) >> 8;              // 196 ranges
  const int nbinA = (E + CHUNK - 1) / CHUNK;  // 196
  const int ntiles1 = (N + 63) / 64;          // 782 gemm1 tiles

  char* base = (char*)d_ws;
  size_t off = 0;
  auto carve = [&](size_t bytes) {
    char* p = base + off;
    off += (bytes + 255) & ~(size_t)255;
    return p;
  };
  float* dinv = (float*)carve((size_t)N * 4);
  int2* rowrange = (int2*)carve((size_t)N * 8);
  int* bincursor = (int*)carve(256 * 4);
  unsigned* binbuf = (unsigned*)carve((size_t)NR * CAPB * 4 + CAPB * 4);
  unsigned* recs = (unsigned*)carve((size_t)NR * CAPB * 4 + 1024);
  unsigned short* h1 = (unsigned short*)carve((size_t)N * DHID * 2);  // bf16
  unsigned short* h2 = (unsigned short*)carve((size_t)N * DOUT * 2);  // bf16
  unsigned short* Wf1 = (unsigned short*)carve((size_t)DIN * DHID * 2);
  unsigned short* Wf2 = (unsigned short*)carve((size_t)DHID * DOUT * 2);

  init_kernel<<<13, 256, 0, stream>>>(W1, W2, Wf1, Wf2, bincursor);
  phaseA_kernel<<<nbinA + ntiles1, 256, 0, stream>>>(
      src, dst, bincursor, binbuf, E, nbinA, x, Wf1, h1, N);
  scan_local_kernel<<<NR, 256, 0, stream>>>(binbuf, bincursor, rowrange, dinv, N);
  binB_kernel<<<NR, 256, 0, stream>>>(binbuf, bincursor, rowrange, dinv, recs, N);
  agg1_gemm2_kernel<<<(N + 15) / 16, 256, 0, stream>>>(
      h1, recs, rowrange, dinv, b1, Wf2, h2, N);
  aggregate2_kernel<<<(N + 3) / 4, 256, 0, stream>>>(
      h2, recs, rowrange, dinv, b2, out, N);
}